// Round 1
// baseline (4079.908 us; speedup 1.0000x reference)
//
#include <hip/hip_runtime.h>

#define QN 8192
#define CCH 64
#define NROW 65536   // B*Q*4
#define RB 16        // rows per block in k_main

__device__ __forceinline__ float gelu_f(float x) {
    // jax.nn.gelu default (approximate=True, tanh form)
    float x3 = x * x * x;
    return 0.5f * x * (1.0f + tanhf(0.7978845608028654f * (x + 0.044715f * x3)));
}

// ---------------- K0: conv3x3 (3->64, SAME) + bias, into zero-padded (B,64,66,66)
__global__ __launch_bounds__(256) void k_conv(const float* __restrict__ inp,
                                              const float* __restrict__ ew,
                                              const float* __restrict__ eb,
                                              float* __restrict__ featpad) {
    int idx = blockIdx.x * 256 + threadIdx.x;
    const int total = 2 * CCH * 66 * 66;
    if (idx >= total) return;
    int xx = idx % 66; int t = idx / 66;
    int yy = t % 66;   t /= 66;
    int o  = t % CCH;  int b = t / CCH;
    int y = yy - 1, x = xx - 1;
    float acc = 0.0f;
    if (y >= 0 && y < 64 && x >= 0 && x < 64) {
        acc = eb[o];
        for (int i = 0; i < 3; ++i) {
            const float* ip = inp + ((b * 3 + i) * 64) * 64;
            const float* wp = ew + (o * 3 + i) * 9;
            #pragma unroll
            for (int ky = 0; ky < 3; ++ky) {
                int sy = y + ky - 1;
                if (sy < 0 || sy > 63) continue;
                #pragma unroll
                for (int kx = 0; kx < 3; ++kx) {
                    int sx = x + kx - 1;
                    if (sx < 0 || sx > 63) continue;
                    acc += ip[sy * 64 + sx] * wp[ky * 3 + kx];
                }
            }
        }
    }
    featpad[idx] = acc;
}

// ---------------- K1: per-row prep: ih/iw, rel, mlp_in = [rel0, rel1, s0*64, s1*64]
__global__ __launch_bounds__(256) void k_prep(const float* __restrict__ coord,
                                              const float* __restrict__ scale,
                                              float4* __restrict__ mlp_in,
                                              int2* __restrict__ ihiw) {
    int row = blockIdx.x * 256 + threadIdx.x;
    if (row >= NROW) return;
    int v = row & 3;
    int bq = row >> 2;
    int b = bq >> 13;  // / QN
    float c0 = coord[bq * 2 + 0], c1 = coord[bq * 2 + 1];
    float s0 = scale[bq * 2 + 0], s1 = scale[bq * 2 + 1];
    float s00 = scale[(b * QN) * 2 + 0];
    float s01 = scale[(b * QN) * 2 + 1];
    float rx = (1.0f - s00) / 63.0f;   // 1/tx
    float ry = (1.0f - s01) / 63.0f;
    float vx = (v & 2) ? 1.0f : -1.0f;
    float vy = (v & 1) ? 1.0f : -1.0f;
    float cc0 = c0 + vx * rx + 1e-6f;
    float cc1 = c1 + vy * ry + 1e-6f;
    cc0 = fminf(fmaxf(cc0, -1.0f + 1e-6f), 1.0f - 1e-6f);
    cc1 = fminf(fmaxf(cc1, -1.0f + 1e-6f), 1.0f - 1e-6f);
    // nearest: round-half-even like jnp.round
    int ih = (int)rintf((cc0 + 1.0f) * 32.0f - 0.5f);
    int iw = (int)rintf((cc1 + 1.0f) * 32.0f - 0.5f);
    ih = min(max(ih, 0), 63);
    iw = min(max(iw, 0), 63);
    float ck0 = (2.0f * (float)ih + 1.0f) / 64.0f - 1.0f;
    float ck1 = (2.0f * (float)iw + 1.0f) / 64.0f - 1.0f;
    float rel0 = (c0 - ck0) * 64.0f;
    float rel1 = (c1 - ck1) * 64.0f;
    mlp_in[row] = make_float4(rel0, rel1, s0 * 64.0f, s1 * 64.0f);
    ihiw[row] = make_int2(ih, iw);
}

// ---------------- K2: fused imnet MLP + value gather + einsum + score, per 16 rows
__global__ __launch_bounds__(256) void k_main(const float* __restrict__ featpad,
                                              const float4* __restrict__ mlp_in,
                                              const int2* __restrict__ ihiw,
                                              const float* __restrict__ iw0, const float* __restrict__ ib0,
                                              const float* __restrict__ iw1, const float* __restrict__ ib1,
                                              const float* __restrict__ iw2, const float* __restrict__ ib2,
                                              const float* __restrict__ sw0, const float* __restrict__ sb0,
                                              const float* __restrict__ sw1, const float* __restrict__ sb1,
                                              float* __restrict__ stacked) {
    // LDS pool: s_val (16*576 f32 = 36864B) aliases s_h0 (16*256 f32, dead by then);
    // s_h1 lives at the tail. Total 53248B (+ small statics) < 64KB.
    __shared__ __align__(16) char pool[36864 + 16384];
    float* s_val = (float*)pool;             // [16][576], phase 4-5
    float* s_h0  = (float*)pool;             // [16][256], phase 2-3 (aliases s_val)
    float* s_h1  = (float*)(pool + 36864);   // [16][256], phase 3-5
    __shared__ float4 s_min[RB];
    __shared__ int2   s_ihiw[RB];
    __shared__ float  s_pred[RB][3];
    __shared__ float  s_score[RB];

    const int t = threadIdx.x;
    const int rowbase = blockIdx.x * RB;

    if (t < RB) {
        s_min[t] = mlp_in[rowbase + t];
        s_ihiw[t] = ihiw[rowbase + t];
        s_score[t] = 0.0f;
    }
    if (t < RB * 3) s_pred[t / 3][t % 3] = 0.0f;
    __syncthreads();

    // ---- phase h0 (4->256) + score MLP hidden (2->256->1 partials)
    {
        float w0 = iw0[t], w1 = iw0[256 + t], w2 = iw0[512 + t], w3 = iw0[768 + t];
        float bb = ib0[t];
        float q0 = sw0[t], q1 = sw0[256 + t], qb = sb0[t], q2 = sw1[t];
        #pragma unroll
        for (int r = 0; r < RB; ++r) {
            float4 m = s_min[r];
            s_h0[r * 256 + t] = gelu_f(m.x * w0 + m.y * w1 + m.z * w2 + m.w * w3 + bb);
            float hs = gelu_f(m.x * q0 + m.y * q1 + qb);
            atomicAdd(&s_score[r], hs * q2);
        }
    }
    __syncthreads();

    // ---- phase h1 (256->256): thread t = hidden column t
    {
        float acc[RB];
        #pragma unroll
        for (int r = 0; r < RB; ++r) acc[r] = 0.0f;
        #pragma unroll 1
        for (int j = 0; j < 256; j += 4) {
            float w0 = iw1[(j + 0) * 256 + t];
            float w1 = iw1[(j + 1) * 256 + t];
            float w2 = iw1[(j + 2) * 256 + t];
            float w3 = iw1[(j + 3) * 256 + t];
            #pragma unroll
            for (int r = 0; r < RB; ++r) {
                float4 h = *(const float4*)(s_h0 + r * 256 + j);
                acc[r] += h.x * w0 + h.y * w1 + h.z * w2 + h.w * w3;
            }
        }
        float bb = ib1[t];
        __syncthreads();   // h0 reads done everywhere before h1 writes? h1 is separate region; this barrier is for s_val alias below
        #pragma unroll
        for (int r = 0; r < RB; ++r) s_h1[r * 256 + t] = gelu_f(acc[r] + bb);
    }
    __syncthreads();

    // ---- value gather into s_val (aliases dead s_h0)
    for (int idx = t; idx < RB * 576; idx += 256) {
        int r = idx / 576, cf = idx % 576;
        int cch = cf / 9, tap = cf % 9;
        int di = tap / 3, dj = tap % 3;
        int row = rowbase + r;
        int b = row >> 15;  // / (QN*4)
        int2 p = s_ihiw[r];
        s_val[r * 576 + cf] = featpad[((b * CCH + cch) * 66 + (p.x + di)) * 66 + (p.y + dj)];
    }
    __syncthreads();

    // ---- GEMM3 (256 -> 1728) fused with value-dot; thread t owns cf = t, t+256, t+512
    for (int m = 0; m < 3; ++m) {
        int cf = t + 256 * m;
        if (cf >= 576) break;
        float vv[RB];
        #pragma unroll
        for (int r = 0; r < RB; ++r) vv[r] = s_val[r * 576 + cf];
        float acc0[RB], acc1[RB], acc2[RB];
        #pragma unroll
        for (int r = 0; r < RB; ++r) { acc0[r] = 0.0f; acc1[r] = 0.0f; acc2[r] = 0.0f; }
        const float* wcol = iw2 + cf * 3;   // wcol[j*1728 + k]
        #pragma unroll 1
        for (int j = 0; j < 256; j += 4) {
            float w00 = wcol[(j + 0) * 1728 + 0], w01 = wcol[(j + 0) * 1728 + 1], w02 = wcol[(j + 0) * 1728 + 2];
            float w10 = wcol[(j + 1) * 1728 + 0], w11 = wcol[(j + 1) * 1728 + 1], w12 = wcol[(j + 1) * 1728 + 2];
            float w20 = wcol[(j + 2) * 1728 + 0], w21 = wcol[(j + 2) * 1728 + 1], w22 = wcol[(j + 2) * 1728 + 2];
            float w30 = wcol[(j + 3) * 1728 + 0], w31 = wcol[(j + 3) * 1728 + 1], w32 = wcol[(j + 3) * 1728 + 2];
            #pragma unroll
            for (int r = 0; r < RB; ++r) {
                float4 h = *(const float4*)(s_h1 + r * 256 + j);
                acc0[r] += h.x * w00 + h.y * w10 + h.z * w20 + h.w * w30;
                acc1[r] += h.x * w01 + h.y * w11 + h.z * w21 + h.w * w31;
                acc2[r] += h.x * w02 + h.y * w12 + h.z * w22 + h.w * w32;
            }
        }
        float b0 = ib2[cf * 3 + 0], b1 = ib2[cf * 3 + 1], b2 = ib2[cf * 3 + 2];
        #pragma unroll
        for (int r = 0; r < RB; ++r) {
            float vr = vv[r];
            atomicAdd(&s_pred[r][0], (acc0[r] + b0) * vr);
            atomicAdd(&s_pred[r][1], (acc1[r] + b1) * vr);
            atomicAdd(&s_pred[r][2], (acc2[r] + b2) * vr);
        }
    }
    __syncthreads();

    // ---- write stacked[bq][k][v]
    if (t < RB * 3) {
        int r = t / 3, k = t % 3;
        int row = rowbase + r;
        int bq = row >> 2, v = row & 3;
        stacked[bq * 12 + k * 4 + v] = s_pred[r][k] + s_score[r] + sb1[0];
    }
}

// ---------------- K3: weight MLP (4->256->1) over B*Q*3 rows
__global__ __launch_bounds__(256) void k_wmlp(const float* __restrict__ stacked,
                                              const float* __restrict__ ww0, const float* __restrict__ wb0,
                                              const float* __restrict__ ww1, const float* __restrict__ wb1,
                                              float* __restrict__ out) {
    int idx = blockIdx.x * 256 + threadIdx.x;
    if (idx >= 16384 * 3) return;
    int k = idx % 3, bq = idx / 3;
    float4 xv = *(const float4*)(stacked + bq * 12 + k * 4);
    float acc = wb1[0];
    #pragma unroll 4
    for (int t = 0; t < 256; ++t) {
        float h = gelu_f(xv.x * ww0[t] + xv.y * ww0[256 + t] + xv.z * ww0[512 + t] + xv.w * ww0[768 + t] + wb0[t]);
        acc += h * ww1[t];
    }
    out[idx] = acc;
}

extern "C" void kernel_launch(void* const* d_in, const int* in_sizes, int n_in,
                              void* d_out, int out_size, void* d_ws, size_t ws_size,
                              hipStream_t stream) {
    const float* inp   = (const float*)d_in[0];
    const float* coord = (const float*)d_in[1];
    const float* scale = (const float*)d_in[2];
    const float* ew    = (const float*)d_in[3];
    const float* eb    = (const float*)d_in[4];
    const float* iw0   = (const float*)d_in[5];
    const float* ib0   = (const float*)d_in[6];
    const float* iw1   = (const float*)d_in[7];
    const float* ib1   = (const float*)d_in[8];
    const float* iw2   = (const float*)d_in[9];
    const float* ib2   = (const float*)d_in[10];
    const float* sw0   = (const float*)d_in[11];
    const float* sb0   = (const float*)d_in[12];
    const float* sw1   = (const float*)d_in[13];
    const float* sb1   = (const float*)d_in[14];
    const float* ww0   = (const float*)d_in[15];
    const float* wb0   = (const float*)d_in[16];
    const float* ww1   = (const float*)d_in[17];
    const float* wb1   = (const float*)d_in[18];
    float* out = (float*)d_out;

    char* ws = (char*)d_ws;
    float*  featpad = (float*)(ws + 0);          // 2*64*66*66*4      = 2,230,272
    float4* mlp_in  = (float4*)(ws + 2230272);   // 65536*16          = 1,048,576
    int2*   ihiw    = (int2*)(ws + 3278848);     // 65536*8           =   524,288
    float*  stacked = (float*)(ws + 3803136);    // 16384*12*4        =   786,432

    k_conv<<<dim3(2179), dim3(256), 0, stream>>>(inp, ew, eb, featpad);
    k_prep<<<dim3(256), dim3(256), 0, stream>>>(coord, scale, mlp_in, ihiw);
    k_main<<<dim3(4096), dim3(256), 0, stream>>>(featpad, mlp_in, ihiw,
                                                 iw0, ib0, iw1, ib1, iw2, ib2,
                                                 sw0, sb0, sw1, sb1, stacked);
    k_wmlp<<<dim3(192), dim3(256), 0, stream>>>(stacked, ww0, wb0, ww1, wb1, out);
}

// Round 2
// 515.121 us; speedup vs baseline: 7.9203x; 7.9203x over previous
//
#include <hip/hip_runtime.h>

#define QN 8192
#define CCH 64
#define NROW 65536   // B*Q*4
#define MR 32        // rows per block in k_main2
#define H0S 264      // padded LDS row stride (f16) for h0/h1: breaks bank conflicts
#define VSTR 584     // padded LDS row stride (f16) for value

typedef _Float16 f16x8 __attribute__((ext_vector_type(8)));
typedef float f32x4 __attribute__((ext_vector_type(4)));

__device__ __forceinline__ float gelu_f(float x) {
    float x3 = x * x * x;
    return 0.5f * x * (1.0f + tanhf(0.7978845608028654f * (x + 0.044715f * x3)));
}

// ---------------- K0: conv3x3 (3->64, SAME) + bias, into zero-padded (B,64,66,66)
__global__ __launch_bounds__(256) void k_conv(const float* __restrict__ inp,
                                              const float* __restrict__ ew,
                                              const float* __restrict__ eb,
                                              float* __restrict__ featpad) {
    int idx = blockIdx.x * 256 + threadIdx.x;
    const int total = 2 * CCH * 66 * 66;
    if (idx >= total) return;
    int xx = idx % 66; int t = idx / 66;
    int yy = t % 66;   t /= 66;
    int o  = t % CCH;  int b = t / CCH;
    int y = yy - 1, x = xx - 1;
    float acc = 0.0f;
    if (y >= 0 && y < 64 && x >= 0 && x < 64) {
        acc = eb[o];
        for (int i = 0; i < 3; ++i) {
            const float* ip = inp + ((b * 3 + i) * 64) * 64;
            const float* wp = ew + (o * 3 + i) * 9;
            #pragma unroll
            for (int ky = 0; ky < 3; ++ky) {
                int sy = y + ky - 1;
                if (sy < 0 || sy > 63) continue;
                #pragma unroll
                for (int kx = 0; kx < 3; ++kx) {
                    int sx = x + kx - 1;
                    if (sx < 0 || sx > 63) continue;
                    acc += ip[sy * 64 + sx] * wp[ky * 3 + kx];
                }
            }
        }
    }
    featpad[idx] = acc;
}

// ---------------- K1: per-row prep
__global__ __launch_bounds__(256) void k_prep(const float* __restrict__ coord,
                                              const float* __restrict__ scale,
                                              float4* __restrict__ mlp_in,
                                              int2* __restrict__ ihiw) {
    int row = blockIdx.x * 256 + threadIdx.x;
    if (row >= NROW) return;
    int v = row & 3;
    int bq = row >> 2;
    int b = bq >> 13;
    float c0 = coord[bq * 2 + 0], c1 = coord[bq * 2 + 1];
    float s0 = scale[bq * 2 + 0], s1 = scale[bq * 2 + 1];
    float s00 = scale[(b * QN) * 2 + 0];
    float s01 = scale[(b * QN) * 2 + 1];
    float rx = (1.0f - s00) / 63.0f;
    float ry = (1.0f - s01) / 63.0f;
    float vx = (v & 2) ? 1.0f : -1.0f;
    float vy = (v & 1) ? 1.0f : -1.0f;
    float cc0 = c0 + vx * rx + 1e-6f;
    float cc1 = c1 + vy * ry + 1e-6f;
    cc0 = fminf(fmaxf(cc0, -1.0f + 1e-6f), 1.0f - 1e-6f);
    cc1 = fminf(fmaxf(cc1, -1.0f + 1e-6f), 1.0f - 1e-6f);
    int ih = (int)rintf((cc0 + 1.0f) * 32.0f - 0.5f);
    int iw = (int)rintf((cc1 + 1.0f) * 32.0f - 0.5f);
    ih = min(max(ih, 0), 63);
    iw = min(max(iw, 0), 63);
    float ck0 = (2.0f * (float)ih + 1.0f) / 64.0f - 1.0f;
    float ck1 = (2.0f * (float)iw + 1.0f) / 64.0f - 1.0f;
    float rel0 = (c0 - ck0) * 64.0f;
    float rel1 = (c1 - ck1) * 64.0f;
    mlp_in[row] = make_float4(rel0, rel1, s0 * 64.0f, s1 * 64.0f);
    ihiw[row] = make_int2(ih, iw);
}

// ---------------- K1b: weight convert+transpose to fp16 n-major
// w1t[n][k] = iw1[k][n] (256x256), w2t[n][k] = iw2[k][n] (1728 x 256)
__global__ __launch_bounds__(256) void k_cvt(const float* __restrict__ iw1,
                                             const float* __restrict__ iw2,
                                             _Float16* __restrict__ w1t,
                                             _Float16* __restrict__ w2t) {
    int idx = blockIdx.x * 256 + threadIdx.x;
    if (idx < 65536) {
        int k = idx >> 8, n = idx & 255;
        w1t[n * 256 + k] = (_Float16)iw1[idx];
    }
    int j = idx - 65536;
    if (j >= 0 && j < 442368) {
        int k = j / 1728, n = j % 1728;
        w2t[n * 256 + k] = (_Float16)iw2[j];
    }
}

// ---------------- K2: fused imnet MLP (MFMA) + value gather + einsum + score
__global__ __launch_bounds__(256, 2) void k_main2(
        const float* __restrict__ featpad,
        const float4* __restrict__ mlp_in,
        const int2* __restrict__ ihiw,
        const _Float16* __restrict__ w1t,
        const _Float16* __restrict__ w2t,
        const float* __restrict__ iw0, const float* __restrict__ ib0,
        const float* __restrict__ ib1, const float* __restrict__ ib2,
        const float* __restrict__ sw0, const float* __restrict__ sb0,
        const float* __restrict__ sw1, const float* __restrict__ sb1,
        float* __restrict__ stacked) {
    // pool: s_val [32][584] f16 (37376 B) aliases s_h0 [32][264] f16 (16896 B);
    // s_h1 [32][264] f16 at tail. total 54272 B.
    __shared__ __align__(16) char pool[37376 + 16896];
    _Float16* s_val = (_Float16*)pool;
    _Float16* s_h0  = (_Float16*)pool;
    _Float16* s_h1  = (_Float16*)(pool + 37376);
    __shared__ float4 s_min[MR];
    __shared__ int2   s_ihiw[MR];
    __shared__ float  s_pred[MR][3];
    __shared__ float  s_score[MR];

    const int t = threadIdx.x;
    const int wave = t >> 6;
    const int lane = t & 63;
    const int quad = lane >> 4;
    const int l15  = lane & 15;
    const int rowbase = blockIdx.x * MR;

    if (t < MR) {
        s_min[t] = mlp_in[rowbase + t];
        s_ihiw[t] = ihiw[rowbase + t];
        s_score[t] = 0.0f;
    }
    if (t < MR * 3) s_pred[t / 3][t % 3] = 0.0f;
    __syncthreads();

    // ---- phase h0 (4->256, fp32 VALU, cast f16) + score MLP (2->256->1)
    {
        float w0 = iw0[t], w1 = iw0[256 + t], w2 = iw0[512 + t], w3 = iw0[768 + t];
        float bb = ib0[t];
        float q0 = sw0[t], q1 = sw0[256 + t], qb = sb0[t], q2 = sw1[t];
        #pragma unroll 4
        for (int r = 0; r < MR; ++r) {
            float4 m = s_min[r];
            s_h0[r * H0S + t] = (_Float16)gelu_f(m.x * w0 + m.y * w1 + m.z * w2 + m.w * w3 + bb);
            float hs = gelu_f(m.x * q0 + m.y * q1 + qb) * q2;
            #pragma unroll
            for (int mm = 1; mm < 64; mm <<= 1) hs += __shfl_xor(hs, mm, 64);
            if (lane == 0) atomicAdd(&s_score[r], hs);
        }
    }
    __syncthreads();

    // ---- phase h1 (256->256) via MFMA; wave handles col-tiles wave*4 .. wave*4+3
    {
        f16x8 a[2][8];
        #pragma unroll
        for (int rt = 0; rt < 2; ++rt)
            #pragma unroll
            for (int kf = 0; kf < 8; ++kf)
                a[rt][kf] = *(const f16x8*)(s_h0 + (rt * 16 + l15) * H0S + kf * 32 + quad * 8);
        #pragma unroll 1
        for (int c = 0; c < 4; ++c) {
            int ctn = (wave * 4 + c) * 16;
            int col = ctn + l15;
            f16x8 b[8];
            #pragma unroll
            for (int kf = 0; kf < 8; ++kf)
                b[kf] = *(const f16x8*)(w1t + col * 256 + kf * 32 + quad * 8);
            f32x4 acc0 = {0.f, 0.f, 0.f, 0.f};
            f32x4 acc1 = {0.f, 0.f, 0.f, 0.f};
            #pragma unroll
            for (int kf = 0; kf < 8; ++kf) {
                acc0 = __builtin_amdgcn_mfma_f32_16x16x32_f16(a[0][kf], b[kf], acc0, 0, 0, 0);
                acc1 = __builtin_amdgcn_mfma_f32_16x16x32_f16(a[1][kf], b[kf], acc1, 0, 0, 0);
            }
            float bias = ib1[col];
            #pragma unroll
            for (int reg = 0; reg < 4; ++reg) {
                int row0 = quad * 4 + reg;
                s_h1[row0 * H0S + col]        = (_Float16)gelu_f(acc0[reg] + bias);
                s_h1[(16 + row0) * H0S + col] = (_Float16)gelu_f(acc1[reg] + bias);
            }
        }
    }
    __syncthreads();   // h0 reads done; s_val may now overwrite pool head

    // ---- value gather into s_val (fp16)
    for (int idx = t; idx < MR * 576; idx += 256) {
        int r = idx / 576, cf = idx - r * 576;
        int cch = cf / 9, tap = cf - cch * 9;
        int di = tap / 3, dj = tap - di * 3;
        int row = rowbase + r;
        int b = row >> 15;
        int2 p = s_ihiw[r];
        s_val[r * VSTR + cf] = (_Float16)featpad[((b * CCH + cch) * 66 + (p.x + di)) * 66 + (p.y + dj)];
    }
    __syncthreads();

    // ---- GEMM3 (256->1728) via MFMA, fused value-dot epilogue
    {
        f16x8 A3[2][8];
        #pragma unroll
        for (int rt = 0; rt < 2; ++rt)
            #pragma unroll
            for (int kf = 0; kf < 8; ++kf)
                A3[rt][kf] = *(const f16x8*)(s_h1 + (rt * 16 + l15) * H0S + kf * 32 + quad * 8);

        float part[2][4][3];
        #pragma unroll
        for (int rt = 0; rt < 2; ++rt)
            #pragma unroll
            for (int reg = 0; reg < 4; ++reg)
                part[rt][reg][0] = part[rt][reg][1] = part[rt][reg][2] = 0.0f;

        const int colbase = wave * 432;
        #pragma unroll 1
        for (int ct = 0; ct < 27; ++ct) {
            int nb = colbase + ct * 16;
            int n = nb + l15;
            f16x8 b[8];
            #pragma unroll
            for (int kf = 0; kf < 8; ++kf)
                b[kf] = *(const f16x8*)(w2t + (size_t)n * 256 + kf * 32 + quad * 8);
            f32x4 acc0 = {0.f, 0.f, 0.f, 0.f};
            f32x4 acc1 = {0.f, 0.f, 0.f, 0.f};
            #pragma unroll
            for (int kf = 0; kf < 8; ++kf) {
                acc0 = __builtin_amdgcn_mfma_f32_16x16x32_f16(A3[0][kf], b[kf], acc0, 0, 0, 0);
                acc1 = __builtin_amdgcn_mfma_f32_16x16x32_f16(A3[1][kf], b[kf], acc1, 0, 0, 0);
            }
            float b2 = ib2[n];
            int cf = n / 3;
            int kl = n - cf * 3;
            float c0[4], c1[4];
            #pragma unroll
            for (int reg = 0; reg < 4; ++reg) {
                int row0 = quad * 4 + reg;
                c0[reg] = (acc0[reg] + b2) * (float)s_val[row0 * VSTR + cf];
                c1[reg] = (acc1[reg] + b2) * (float)s_val[(16 + row0) * VSTR + cf];
            }
            if (kl == 0) {
                #pragma unroll
                for (int reg = 0; reg < 4; ++reg) { part[0][reg][0] += c0[reg]; part[1][reg][0] += c1[reg]; }
            } else if (kl == 1) {
                #pragma unroll
                for (int reg = 0; reg < 4; ++reg) { part[0][reg][1] += c0[reg]; part[1][reg][1] += c1[reg]; }
            } else {
                #pragma unroll
                for (int reg = 0; reg < 4; ++reg) { part[0][reg][2] += c0[reg]; part[1][reg][2] += c1[reg]; }
            }
        }

        // reduce across the 16 column-lanes of each quad, then cross-wave via LDS atomics
        #pragma unroll
        for (int rt = 0; rt < 2; ++rt)
            #pragma unroll
            for (int reg = 0; reg < 4; ++reg)
                #pragma unroll
                for (int k = 0; k < 3; ++k) {
                    float v = part[rt][reg][k];
                    #pragma unroll
                    for (int mm = 1; mm < 16; mm <<= 1) v += __shfl_xor(v, mm, 64);
                    if (l15 == 0) atomicAdd(&s_pred[rt * 16 + quad * 4 + reg][k], v);
                }
    }
    __syncthreads();

    // ---- write stacked[bq][k][v]
    if (t < MR * 3) {
        int r = t / 3, k = t - r * 3;
        int row = rowbase + r;
        int bq = row >> 2, v = row & 3;
        stacked[bq * 12 + k * 4 + v] = s_pred[r][k] + s_score[r] + sb1[0];
    }
}

// ---------------- K3: weight MLP (4->256->1) over B*Q*3 rows
__global__ __launch_bounds__(256) void k_wmlp(const float* __restrict__ stacked,
                                              const float* __restrict__ ww0, const float* __restrict__ wb0,
                                              const float* __restrict__ ww1, const float* __restrict__ wb1,
                                              float* __restrict__ out) {
    int idx = blockIdx.x * 256 + threadIdx.x;
    if (idx >= 16384 * 3) return;
    int k = idx % 3, bq = idx / 3;
    float4 xv = *(const float4*)(stacked + bq * 12 + k * 4);
    float acc = wb1[0];
    #pragma unroll 4
    for (int t = 0; t < 256; ++t) {
        float h = gelu_f(xv.x * ww0[t] + xv.y * ww0[256 + t] + xv.z * ww0[512 + t] + xv.w * ww0[768 + t] + wb0[t]);
        acc += h * ww1[t];
    }
    out[idx] = acc;
}

extern "C" void kernel_launch(void* const* d_in, const int* in_sizes, int n_in,
                              void* d_out, int out_size, void* d_ws, size_t ws_size,
                              hipStream_t stream) {
    const float* inp   = (const float*)d_in[0];
    const float* coord = (const float*)d_in[1];
    const float* scale = (const float*)d_in[2];
    const float* ew    = (const float*)d_in[3];
    const float* eb    = (const float*)d_in[4];
    const float* iw0   = (const float*)d_in[5];
    const float* ib0   = (const float*)d_in[6];
    const float* iw1   = (const float*)d_in[7];
    const float* ib1   = (const float*)d_in[8];
    const float* iw2   = (const float*)d_in[9];
    const float* ib2   = (const float*)d_in[10];
    const float* sw0   = (const float*)d_in[11];
    const float* sb0   = (const float*)d_in[12];
    const float* sw1   = (const float*)d_in[13];
    const float* sb1   = (const float*)d_in[14];
    const float* ww0   = (const float*)d_in[15];
    const float* wb0   = (const float*)d_in[16];
    const float* ww1   = (const float*)d_in[17];
    const float* wb1   = (const float*)d_in[18];
    float* out = (float*)d_out;

    char* ws = (char*)d_ws;
    float*     featpad = (float*)(ws + 0);          // 2,230,272
    float4*    mlp_in  = (float4*)(ws + 2230272);   // 1,048,576
    int2*      ihiw    = (int2*)(ws + 3278848);     //   524,288
    float*     stacked = (float*)(ws + 3803136);    //   786,432
    _Float16*  w1t     = (_Float16*)(ws + 4589568); //   131,072
    _Float16*  w2t     = (_Float16*)(ws + 4720640); //   884,736  (end 5,605,376)

    k_conv<<<dim3(2179), dim3(256), 0, stream>>>(inp, ew, eb, featpad);
    k_prep<<<dim3(256), dim3(256), 0, stream>>>(coord, scale, mlp_in, ihiw);
    k_cvt<<<dim3(1984), dim3(256), 0, stream>>>(iw1, iw2, w1t, w2t);
    k_main2<<<dim3(NROW / MR), dim3(256), 0, stream>>>(featpad, mlp_in, ihiw, w1t, w2t,
                                                       iw0, ib0, ib1, ib2,
                                                       sw0, sb0, sw1, sb1, stacked);
    k_wmlp<<<dim3(192), dim3(256), 0, stream>>>(stacked, ww0, wb0, ww1, wb1, out);
}

// Round 3
// 430.079 us; speedup vs baseline: 9.4864x; 1.1977x over previous
//
#include <hip/hip_runtime.h>

#define QN 8192
#define CCH 64
#define NROW 65536   // B*Q*4
#define MR 32        // rows per block
#define H0S 264      // LDS f16 stride for h0 staging (k_h01)
#define VSTR 36      // s_valT row stride in f16 ([576][36])

typedef _Float16 f16x8 __attribute__((ext_vector_type(8)));
typedef _Float16 f16x4 __attribute__((ext_vector_type(4)));
typedef float f32x4 __attribute__((ext_vector_type(4)));

// gelu(x) = 0.5x(1+tanh(0.79788456(x+0.044715x^3))) = x*e/(1+e), e = exp(1.59576912*x*(1+0.044715x^2))
__device__ __forceinline__ float gelu_f(float x) {
    float x2 = x * x;
    float tt = fmaf(0.044715f, x2, 1.0f);
    float e = __expf(1.5957691216f * x * tt);
    float r = __builtin_amdgcn_rcpf(1.0f + e);
    return x - x * r;
}

// ---------------- K0: conv3x3 (3->64) + bias, into zero-padded channel-LAST (B,66,66,64)
__global__ __launch_bounds__(256) void k_conv(const float* __restrict__ inp,
                                              const float* __restrict__ ew,
                                              const float* __restrict__ eb,
                                              float* __restrict__ featpad) {
    int idx = blockIdx.x * 256 + threadIdx.x;
    const int total = 2 * 66 * 66 * CCH;
    if (idx >= total) return;
    int o = idx & 63; int pix = idx >> 6;
    int xx = pix % 66; int t2 = pix / 66;
    int yy = t2 % 66;  int b = t2 / 66;
    int y = yy - 1, x = xx - 1;
    float acc = 0.0f;
    if (y >= 0 && y < 64 && x >= 0 && x < 64) {
        acc = eb[o];
        for (int i = 0; i < 3; ++i) {
            const float* ip = inp + ((b * 3 + i) * 64) * 64;
            const float* wp = ew + (o * 3 + i) * 9;
            #pragma unroll
            for (int ky = 0; ky < 3; ++ky) {
                int sy = y + ky - 1;
                if (sy < 0 || sy > 63) continue;
                #pragma unroll
                for (int kx = 0; kx < 3; ++kx) {
                    int sx = x + kx - 1;
                    if (sx < 0 || sx > 63) continue;
                    acc += ip[sy * 64 + sx] * wp[ky * 3 + kx];
                }
            }
        }
    }
    featpad[idx] = acc;
}

// ---------------- K1: per-row prep + score MLP (2->256->1), score folded with sb1
__global__ __launch_bounds__(256) void k_prep(const float* __restrict__ coord,
                                              const float* __restrict__ scale,
                                              const float* __restrict__ sw0,
                                              const float* __restrict__ sb0,
                                              const float* __restrict__ sw1,
                                              const float* __restrict__ sb1,
                                              float4* __restrict__ mlp_in,
                                              int2* __restrict__ ihiw,
                                              float* __restrict__ scoreg) {
    int row = blockIdx.x * 256 + threadIdx.x;
    if (row >= NROW) return;
    int v = row & 3;
    int bq = row >> 2;
    int b = bq >> 13;
    float c0 = coord[bq * 2 + 0], c1 = coord[bq * 2 + 1];
    float s0 = scale[bq * 2 + 0], s1 = scale[bq * 2 + 1];
    float s00 = scale[(b * QN) * 2 + 0];
    float s01 = scale[(b * QN) * 2 + 1];
    float rx = (1.0f - s00) / 63.0f;
    float ry = (1.0f - s01) / 63.0f;
    float vx = (v & 2) ? 1.0f : -1.0f;
    float vy = (v & 1) ? 1.0f : -1.0f;
    float cc0 = c0 + vx * rx + 1e-6f;
    float cc1 = c1 + vy * ry + 1e-6f;
    cc0 = fminf(fmaxf(cc0, -1.0f + 1e-6f), 1.0f - 1e-6f);
    cc1 = fminf(fmaxf(cc1, -1.0f + 1e-6f), 1.0f - 1e-6f);
    int ih = (int)rintf((cc0 + 1.0f) * 32.0f - 0.5f);
    int iw = (int)rintf((cc1 + 1.0f) * 32.0f - 0.5f);
    ih = min(max(ih, 0), 63);
    iw = min(max(iw, 0), 63);
    float ck0 = (2.0f * (float)ih + 1.0f) / 64.0f - 1.0f;
    float ck1 = (2.0f * (float)iw + 1.0f) / 64.0f - 1.0f;
    float rel0 = (c0 - ck0) * 64.0f;
    float rel1 = (c1 - ck1) * 64.0f;
    mlp_in[row] = make_float4(rel0, rel1, s0 * 64.0f, s1 * 64.0f);
    ihiw[row] = make_int2(ih, iw);
    // score MLP: serial 256-dot per row (weight loads are wave-uniform -> scalar)
    float sc = sb1[0];
    #pragma unroll 4
    for (int t2 = 0; t2 < 256; ++t2) {
        float h = gelu_f(fmaf(rel0, sw0[t2], fmaf(rel1, sw0[256 + t2], sb0[t2])));
        sc = fmaf(h, sw1[t2], sc);
    }
    scoreg[row] = sc;
}

// ---------------- K1b: weight convert; w1t[n][k]=iw1[k][n]; w2t permuted n' = k*576 + tap*64 + cch
__global__ __launch_bounds__(256) void k_cvt(const float* __restrict__ iw1,
                                             const float* __restrict__ iw2,
                                             const float* __restrict__ ib2,
                                             _Float16* __restrict__ w1t,
                                             _Float16* __restrict__ w2t,
                                             float* __restrict__ b2p) {
    int idx = blockIdx.x * 256 + threadIdx.x;
    if (idx < 442368) {
        int np = idx >> 8, j = idx & 255;
        int k = np / 576;
        int rem = np - k * 576;
        int tap = rem >> 6, cch = rem & 63;
        int n = (cch * 9 + tap) * 3 + k;
        w2t[idx] = (_Float16)iw2[j * 1728 + n];
        if (j == 0) b2p[np] = ib2[n];
    } else {
        int i2 = idx - 442368;   // < 65536 (grid sized exactly)
        int n = i2 >> 8, kk = i2 & 255;
        w1t[i2] = (_Float16)iw1[kk * 256 + n];
    }
}

// ---------------- K2a: h0 (4->256) + h1 (256->256) MFMA, h1 -> global f16
__global__ __launch_bounds__(256) void k_h01(const float4* __restrict__ mlp_in,
                                             const float* __restrict__ iw0,
                                             const float* __restrict__ ib0,
                                             const _Float16* __restrict__ w1t,
                                             const float* __restrict__ ib1,
                                             _Float16* __restrict__ h1g) {
    __shared__ _Float16 s_h0[MR * H0S];
    __shared__ float4 s_min[MR];
    const int t = threadIdx.x;
    const int wave = t >> 6, lane = t & 63, quad = lane >> 4, l15 = lane & 15;
    const int rowbase = blockIdx.x * MR;

    if (t < MR) s_min[t] = mlp_in[rowbase + t];
    __syncthreads();
    {
        float w0 = iw0[t], w1 = iw0[256 + t], w2 = iw0[512 + t], w3 = iw0[768 + t];
        float bb = ib0[t];
        #pragma unroll 4
        for (int r = 0; r < MR; ++r) {
            float4 m = s_min[r];
            s_h0[r * H0S + t] =
                (_Float16)gelu_f(fmaf(m.x, w0, fmaf(m.y, w1, fmaf(m.z, w2, fmaf(m.w, w3, bb)))));
        }
    }
    __syncthreads();

    f16x8 a[2][8];
    #pragma unroll
    for (int rt = 0; rt < 2; ++rt)
        #pragma unroll
        for (int kf = 0; kf < 8; ++kf)
            a[rt][kf] = *(const f16x8*)(s_h0 + (rt * 16 + l15) * H0S + kf * 32 + quad * 8);
    __syncthreads();   // all A-reads done; s_h0 becomes h1 staging

    #pragma unroll 1
    for (int c = 0; c < 4; ++c) {
        int col = (wave * 4 + c) * 16 + l15;
        f16x8 b[8];
        #pragma unroll
        for (int kf = 0; kf < 8; ++kf)
            b[kf] = *(const f16x8*)(w1t + col * 256 + kf * 32 + quad * 8);
        f32x4 acc0 = {0.f, 0.f, 0.f, 0.f};
        f32x4 acc1 = {0.f, 0.f, 0.f, 0.f};
        #pragma unroll
        for (int kf = 0; kf < 8; ++kf) {
            acc0 = __builtin_amdgcn_mfma_f32_16x16x32_f16(a[0][kf], b[kf], acc0, 0, 0, 0);
            acc1 = __builtin_amdgcn_mfma_f32_16x16x32_f16(a[1][kf], b[kf], acc1, 0, 0, 0);
        }
        float bias = ib1[col];
        #pragma unroll
        for (int reg = 0; reg < 4; ++reg) {
            int r0 = quad * 4 + reg;
            s_h0[r0 * H0S + col]        = (_Float16)gelu_f(acc0[reg] + bias);
            s_h0[(16 + r0) * H0S + col] = (_Float16)gelu_f(acc1[reg] + bias);
        }
    }
    __syncthreads();
    // vectorized flush to global (coalesced 16B)
    #pragma unroll
    for (int c = t; c < MR * 32; c += 256) {
        int row = c >> 5, c8 = c & 31;
        *(f16x8*)(h1g + (size_t)(rowbase + row) * 256 + c8 * 8) =
            *(const f16x8*)(s_h0 + row * H0S + c8 * 8);
    }
}

// ---------------- K2b: GEMM3 (256->1728, permuted cols) + fused value-dot
__global__ __launch_bounds__(256, 3) void k_main3(const float* __restrict__ featpad,
                                                  const _Float16* __restrict__ h1g,
                                                  const int2* __restrict__ ihiw,
                                                  const _Float16* __restrict__ w2t,
                                                  const float* __restrict__ b2p,
                                                  const float* __restrict__ scoreg,
                                                  float* __restrict__ stacked) {
    __shared__ _Float16 s_valT[576 * VSTR];   // [cfp][row], 41472 B
    __shared__ int   s_base[MR];
    __shared__ int   s_dtab[9];
    __shared__ float s_pred[MR][3];
    const int t = threadIdx.x;
    const int wave = t >> 6, lane = t & 63, quad = lane >> 4, l15 = lane & 15;
    const int rowbase = blockIdx.x * MR;

    if (t < MR) {
        int row = rowbase + t;
        int b = row >> 15;
        int2 p = ihiw[row];
        s_base[t] = ((b * 66 + p.x) * 66 + p.y) * 64;
    }
    if (t < 9) { int di = t / 3; s_dtab[t] = (di * 66 + (t - 3 * di)) * 64; }
    if (t < MR * 3) s_pred[t / 3][t % 3] = 0.0f;

    // A fragments straight from global h1 (L2-hot, coalesced 64B/row)
    f16x8 A3[2][8];
    #pragma unroll
    for (int rt = 0; rt < 2; ++rt)
        #pragma unroll
        for (int kf = 0; kf < 8; ++kf)
            A3[rt][kf] = *(const f16x8*)(h1g + (size_t)(rowbase + rt * 16 + l15) * 256 + kf * 32 + quad * 8);

    __syncthreads();
    // gather value (coalesced float4 from channel-last featpad) -> transposed LDS
    #pragma unroll 1
    for (int i4 = t; i4 < MR * 144; i4 += 256) {
        int r = i4 / 144;
        int c4 = i4 - r * 144;
        int tap = c4 >> 4;
        int cch0 = (c4 & 15) << 2;
        const float4 v = *(const float4*)(featpad + s_base[r] + s_dtab[tap] + cch0);
        _Float16* wp = s_valT + (c4 << 2) * VSTR + r;
        wp[0]        = (_Float16)v.x;
        wp[VSTR]     = (_Float16)v.y;
        wp[2 * VSTR] = (_Float16)v.z;
        wp[3 * VSTR] = (_Float16)v.w;
    }
    __syncthreads();

    float p0[2][4], p1[2][4], p2[2][4];
    #pragma unroll
    for (int rt = 0; rt < 2; ++rt)
        #pragma unroll
        for (int reg = 0; reg < 4; ++reg) { p0[rt][reg] = 0.f; p1[rt][reg] = 0.f; p2[rt][reg] = 0.f; }

    #pragma unroll 1
    for (int i = 0; i < 27; ++i) {
        int tile = wave * 27 + i;
        int kt = tile / 36;            // k of this tile (uniform per wave-iter)
        int cfp = (tile - kt * 36) * 16 + l15;
        int np = tile * 16 + l15;
        f16x8 bf[8];
        #pragma unroll
        for (int kf = 0; kf < 8; ++kf)
            bf[kf] = *(const f16x8*)(w2t + (size_t)np * 256 + kf * 32 + quad * 8);
        f32x4 acc0 = {0.f, 0.f, 0.f, 0.f};
        f32x4 acc1 = {0.f, 0.f, 0.f, 0.f};
        #pragma unroll
        for (int kf = 0; kf < 8; ++kf) {
            acc0 = __builtin_amdgcn_mfma_f32_16x16x32_f16(A3[0][kf], bf[kf], acc0, 0, 0, 0);
            acc1 = __builtin_amdgcn_mfma_f32_16x16x32_f16(A3[1][kf], bf[kf], acc1, 0, 0, 0);
        }
        float bv = b2p[np];
        const _Float16* vp = s_valT + cfp * VSTR + quad * 4;
        f16x4 v0 = *(const f16x4*)(vp);
        f16x4 v1 = *(const f16x4*)(vp + 16);
        if (kt == 0) {
            #pragma unroll
            for (int reg = 0; reg < 4; ++reg) {
                float w0f = (float)v0[reg], w1f = (float)v1[reg];
                p0[0][reg] = fmaf(acc0[reg], w0f, fmaf(bv, w0f, p0[0][reg]));
                p0[1][reg] = fmaf(acc1[reg], w1f, fmaf(bv, w1f, p0[1][reg]));
            }
        } else if (kt == 1) {
            #pragma unroll
            for (int reg = 0; reg < 4; ++reg) {
                float w0f = (float)v0[reg], w1f = (float)v1[reg];
                p1[0][reg] = fmaf(acc0[reg], w0f, fmaf(bv, w0f, p1[0][reg]));
                p1[1][reg] = fmaf(acc1[reg], w1f, fmaf(bv, w1f, p1[1][reg]));
            }
        } else {
            #pragma unroll
            for (int reg = 0; reg < 4; ++reg) {
                float w0f = (float)v0[reg], w1f = (float)v1[reg];
                p2[0][reg] = fmaf(acc0[reg], w0f, fmaf(bv, w0f, p2[0][reg]));
                p2[1][reg] = fmaf(acc1[reg], w1f, fmaf(bv, w1f, p2[1][reg]));
            }
        }
    }

    #pragma unroll
    for (int rt = 0; rt < 2; ++rt)
        #pragma unroll
        for (int reg = 0; reg < 4; ++reg) {
            float a0 = p0[rt][reg], a1 = p1[rt][reg], a2 = p2[rt][reg];
            #pragma unroll
            for (int m = 1; m < 16; m <<= 1) {
                a0 += __shfl_xor(a0, m, 64);
                a1 += __shfl_xor(a1, m, 64);
                a2 += __shfl_xor(a2, m, 64);
            }
            if (l15 == 0) {
                int rr = rt * 16 + quad * 4 + reg;
                atomicAdd(&s_pred[rr][0], a0);
                atomicAdd(&s_pred[rr][1], a1);
                atomicAdd(&s_pred[rr][2], a2);
            }
        }
    __syncthreads();

    if (t < MR * 3) {
        int r = t / 3, kk = t % 3;
        int row = rowbase + r;
        int bq = row >> 2, v = row & 3;
        stacked[bq * 12 + kk * 4 + v] = s_pred[r][kk] + scoreg[row];
    }
}

// ---------------- K3: weight MLP (4->256->1) over B*Q*3 rows
__global__ __launch_bounds__(256) void k_wmlp(const float* __restrict__ stacked,
                                              const float* __restrict__ ww0, const float* __restrict__ wb0,
                                              const float* __restrict__ ww1, const float* __restrict__ wb1,
                                              float* __restrict__ out) {
    int idx = blockIdx.x * 256 + threadIdx.x;
    if (idx >= 16384 * 3) return;
    int k = idx % 3, bq = idx / 3;
    float4 xv = *(const float4*)(stacked + bq * 12 + k * 4);
    float acc = wb1[0];
    #pragma unroll 4
    for (int t = 0; t < 256; ++t) {
        float h = gelu_f(fmaf(xv.x, ww0[t], fmaf(xv.y, ww0[256 + t],
                      fmaf(xv.z, ww0[512 + t], fmaf(xv.w, ww0[768 + t], wb0[t])))));
        acc = fmaf(h, ww1[t], acc);
    }
    out[idx] = acc;
}

extern "C" void kernel_launch(void* const* d_in, const int* in_sizes, int n_in,
                              void* d_out, int out_size, void* d_ws, size_t ws_size,
                              hipStream_t stream) {
    const float* inp   = (const float*)d_in[0];
    const float* coord = (const float*)d_in[1];
    const float* scale = (const float*)d_in[2];
    const float* ew    = (const float*)d_in[3];
    const float* eb    = (const float*)d_in[4];
    const float* iw0   = (const float*)d_in[5];
    const float* ib0   = (const float*)d_in[6];
    const float* iw1   = (const float*)d_in[7];
    const float* ib1   = (const float*)d_in[8];
    const float* iw2   = (const float*)d_in[9];
    const float* ib2   = (const float*)d_in[10];
    const float* sw0   = (const float*)d_in[11];
    const float* sb0   = (const float*)d_in[12];
    const float* sw1   = (const float*)d_in[13];
    const float* sb1   = (const float*)d_in[14];
    const float* ww0   = (const float*)d_in[15];
    const float* wb0   = (const float*)d_in[16];
    const float* ww1   = (const float*)d_in[17];
    const float* wb1   = (const float*)d_in[18];
    float* out = (float*)d_out;

    char* ws = (char*)d_ws;
    float*     featpad = (float*)(ws + 0);           // 2,230,272
    float4*    mlp_in  = (float4*)(ws + 2230272);    // 1,048,576
    int2*      ihiw    = (int2*)(ws + 3278848);      //   524,288
    float*     scoreg  = (float*)(ws + 3803136);     //   262,144
    float*     stacked = (float*)(ws + 4065280);     //   786,432
    _Float16*  w1t     = (_Float16*)(ws + 4851712);  //   131,072
    _Float16*  w2t     = (_Float16*)(ws + 4982784);  //   884,736
    float*     b2p     = (float*)(ws + 5867520);     //     6,912
    _Float16*  h1g     = (_Float16*)(ws + 5874432);  // 33,554,432  (end 39,428,864)

    k_conv<<<dim3(2178), dim3(256), 0, stream>>>(inp, ew, eb, featpad);
    k_prep<<<dim3(256), dim3(256), 0, stream>>>(coord, scale, sw0, sb0, sw1, sb1,
                                                mlp_in, ihiw, scoreg);
    k_cvt<<<dim3(1984), dim3(256), 0, stream>>>(iw1, iw2, ib2, w1t, w2t, b2p);
    k_h01<<<dim3(NROW / MR), dim3(256), 0, stream>>>(mlp_in, iw0, ib0, w1t, ib1, h1g);
    k_main3<<<dim3(NROW / MR), dim3(256), 0, stream>>>(featpad, h1g, ihiw, w2t, b2p,
                                                       scoreg, stacked);
    k_wmlp<<<dim3(192), dim3(256), 0, stream>>>(stacked, ww0, wb0, ww1, wb1, out);
}

// Round 4
// 413.962 us; speedup vs baseline: 9.8557x; 1.0389x over previous
//
#include <hip/hip_runtime.h>

#define QN 8192
#define CCH 64
#define NROW 65536   // B*Q*4
#define MR 32        // rows per block
#define H0S 264      // LDS f16 stride for h0/h1 staging
#define VSTR 36      // s_valT row stride in f16 ([576][36])

typedef _Float16 f16x8 __attribute__((ext_vector_type(8)));
typedef _Float16 f16x4 __attribute__((ext_vector_type(4)));
typedef float f32x4 __attribute__((ext_vector_type(4)));

__device__ __forceinline__ float gelu_f(float x) {
    float x2 = x * x;
    float tt = fmaf(0.044715f, x2, 1.0f);
    float e = __expf(1.5957691216f * x * tt);
    float r = __builtin_amdgcn_rcpf(1.0f + e);
    return x - x * r;
}

// ---------------- K_pre: conv (blocks 0..2177) + prep (2178..2433) + cvt (2434..4417)
__global__ __launch_bounds__(256) void k_pre(const float* __restrict__ inp,
                                             const float* __restrict__ ew,
                                             const float* __restrict__ eb,
                                             const float* __restrict__ coord,
                                             const float* __restrict__ scale,
                                             const float* __restrict__ sw0,
                                             const float* __restrict__ sb0,
                                             const float* __restrict__ sw1,
                                             const float* __restrict__ sb1,
                                             const float* __restrict__ iw1,
                                             const float* __restrict__ iw2,
                                             const float* __restrict__ ib2,
                                             float* __restrict__ featpad,
                                             float4* __restrict__ mlp_in,
                                             int2* __restrict__ ihiw,
                                             float* __restrict__ scoreg,
                                             _Float16* __restrict__ w1t,
                                             _Float16* __restrict__ w2t,
                                             float* __restrict__ b2p) {
    const int bb = blockIdx.x;
    const int tt0 = threadIdx.x;
    if (bb < 2178) {
        // conv3x3 (3->64) + bias, zero-padded channel-LAST (B,66,66,64)
        int idx = bb * 256 + tt0;
        const int total = 2 * 66 * 66 * CCH;
        if (idx >= total) return;
        int o = idx & 63; int pix = idx >> 6;
        int xx = pix % 66; int t2 = pix / 66;
        int yy = t2 % 66;  int b = t2 / 66;
        int y = yy - 1, x = xx - 1;
        float acc = 0.0f;
        if (y >= 0 && y < 64 && x >= 0 && x < 64) {
            acc = eb[o];
            for (int i = 0; i < 3; ++i) {
                const float* ip = inp + ((b * 3 + i) * 64) * 64;
                const float* wp = ew + (o * 3 + i) * 9;
                #pragma unroll
                for (int ky = 0; ky < 3; ++ky) {
                    int sy = y + ky - 1;
                    if (sy < 0 || sy > 63) continue;
                    #pragma unroll
                    for (int kx = 0; kx < 3; ++kx) {
                        int sx = x + kx - 1;
                        if (sx < 0 || sx > 63) continue;
                        acc += ip[sy * 64 + sx] * wp[ky * 3 + kx];
                    }
                }
            }
        }
        featpad[idx] = acc;
    } else if (bb < 2434) {
        // per-row prep + score MLP
        int row = (bb - 2178) * 256 + tt0;
        int v = row & 3;
        int bq = row >> 2;
        int b = bq >> 13;
        float c0 = coord[bq * 2 + 0], c1 = coord[bq * 2 + 1];
        float s0 = scale[bq * 2 + 0], s1 = scale[bq * 2 + 1];
        float s00 = scale[(b * QN) * 2 + 0];
        float s01 = scale[(b * QN) * 2 + 1];
        float rx = (1.0f - s00) / 63.0f;
        float ry = (1.0f - s01) / 63.0f;
        float vx = (v & 2) ? 1.0f : -1.0f;
        float vy = (v & 1) ? 1.0f : -1.0f;
        float cc0 = c0 + vx * rx + 1e-6f;
        float cc1 = c1 + vy * ry + 1e-6f;
        cc0 = fminf(fmaxf(cc0, -1.0f + 1e-6f), 1.0f - 1e-6f);
        cc1 = fminf(fmaxf(cc1, -1.0f + 1e-6f), 1.0f - 1e-6f);
        int ih = (int)rintf((cc0 + 1.0f) * 32.0f - 0.5f);
        int iw = (int)rintf((cc1 + 1.0f) * 32.0f - 0.5f);
        ih = min(max(ih, 0), 63);
        iw = min(max(iw, 0), 63);
        float ck0 = (2.0f * (float)ih + 1.0f) / 64.0f - 1.0f;
        float ck1 = (2.0f * (float)iw + 1.0f) / 64.0f - 1.0f;
        float rel0 = (c0 - ck0) * 64.0f;
        float rel1 = (c1 - ck1) * 64.0f;
        mlp_in[row] = make_float4(rel0, rel1, s0 * 64.0f, s1 * 64.0f);
        ihiw[row] = make_int2(ih, iw);
        float sc = sb1[0];
        #pragma unroll 4
        for (int t2 = 0; t2 < 256; ++t2) {
            float h = gelu_f(fmaf(rel0, sw0[t2], fmaf(rel1, sw0[256 + t2], sb0[t2])));
            sc = fmaf(h, sw1[t2], sc);
        }
        scoreg[row] = sc;
    } else {
        // weight convert: w1t[n][k]=iw1[k][n]; w2t permuted n' = k*576 + tap*64 + cch
        int idx = (bb - 2434) * 256 + tt0;
        if (idx < 442368) {
            int np = idx >> 8, j = idx & 255;
            int k = np / 576;
            int rem = np - k * 576;
            int tap = rem >> 6, cch = rem & 63;
            int n = (cch * 9 + tap) * 3 + k;
            w2t[idx] = (_Float16)iw2[j * 1728 + n];
            if (j == 0) b2p[np] = ib2[n];
        } else {
            int i2 = idx - 442368;
            int n = i2 >> 8, kk = i2 & 255;
            w1t[i2] = (_Float16)iw1[kk * 256 + n];
        }
    }
}

#define LOADB2(BF, BV, TILE) do {                                              \
    int np_ = (wave27 + (TILE)) * 16 + l15;                                    \
    const _Float16* wp_ = w2t + (size_t)np_ * 256 + quad * 8;                  \
    _Pragma("unroll")                                                          \
    for (int kf_ = 0; kf_ < 8; ++kf_) BF[kf_] = *(const f16x8*)(wp_ + kf_ * 32);\
    BV = b2p[np_];                                                             \
} while (0)

#define COMPUTE2(BF, BV, TILE) do {                                            \
    int tt_ = wave27 + (TILE);                                                 \
    int kt_ = tt_ / 36;                                                        \
    int cfp_ = (tt_ - kt_ * 36) * 16 + l15;                                    \
    const _Float16* vp_ = s_valT + cfp_ * VSTR + quad * 4;                     \
    f16x4 v0_ = *(const f16x4*)(vp_);                                          \
    f16x4 v1_ = *(const f16x4*)(vp_ + 16);                                     \
    f32x4 acc0_ = {0.f, 0.f, 0.f, 0.f};                                       \
    f32x4 acc1_ = {0.f, 0.f, 0.f, 0.f};                                       \
    _Pragma("unroll")                                                          \
    for (int kf_ = 0; kf_ < 8; ++kf_) {                                        \
        acc0_ = __builtin_amdgcn_mfma_f32_16x16x32_f16(A3[0][kf_], BF[kf_], acc0_, 0, 0, 0); \
        acc1_ = __builtin_amdgcn_mfma_f32_16x16x32_f16(A3[1][kf_], BF[kf_], acc1_, 0, 0, 0); \
    }                                                                          \
    if (kt_ == 0) {                                                            \
        _Pragma("unroll")                                                      \
        for (int rg_ = 0; rg_ < 4; ++rg_) {                                    \
            float w0_ = (float)v0_[rg_], w1_ = (float)v1_[rg_];                \
            p0[0][rg_] = fmaf(acc0_[rg_], w0_, fmaf(BV, w0_, p0[0][rg_]));     \
            p0[1][rg_] = fmaf(acc1_[rg_], w1_, fmaf(BV, w1_, p0[1][rg_]));     \
        }                                                                      \
    } else if (kt_ == 1) {                                                     \
        _Pragma("unroll")                                                      \
        for (int rg_ = 0; rg_ < 4; ++rg_) {                                    \
            float w0_ = (float)v0_[rg_], w1_ = (float)v1_[rg_];                \
            p1[0][rg_] = fmaf(acc0_[rg_], w0_, fmaf(BV, w0_, p1[0][rg_]));     \
            p1[1][rg_] = fmaf(acc1_[rg_], w1_, fmaf(BV, w1_, p1[1][rg_]));     \
        }                                                                      \
    } else {                                                                   \
        _Pragma("unroll")                                                      \
        for (int rg_ = 0; rg_ < 4; ++rg_) {                                    \
            float w0_ = (float)v0_[rg_], w1_ = (float)v1_[rg_];                \
            p2[0][rg_] = fmaf(acc0_[rg_], w0_, fmaf(BV, w0_, p2[0][rg_]));     \
            p2[1][rg_] = fmaf(acc1_[rg_], w1_, fmaf(BV, w1_, p2[1][rg_]));     \
        }                                                                      \
    }                                                                          \
} while (0)

// ---------------- K_fused: h0 -> h1 (MFMA, LDS-resident) -> GEMM3 + value-dot -> +score -> weight MLP
__global__ __launch_bounds__(256) void k_fused(const float* __restrict__ featpad,
                                               const float4* __restrict__ mlp_in,
                                               const int2* __restrict__ ihiw,
                                               const float* __restrict__ iw0,
                                               const float* __restrict__ ib0,
                                               const _Float16* __restrict__ w1t,
                                               const float* __restrict__ ib1,
                                               const _Float16* __restrict__ w2t,
                                               const float* __restrict__ b2p,
                                               const float* __restrict__ scoreg,
                                               const float* __restrict__ ww0,
                                               const float* __restrict__ wb0,
                                               const float* __restrict__ ww1,
                                               const float* __restrict__ wb1,
                                               float* __restrict__ out) {
    // pool: s_valT [576][36] f16 = 41472 B; aliased by s_h0/s_h1 [32][264] f16 = 16896 B
    __shared__ __align__(16) char pool[576 * VSTR * 2];
    _Float16* s_h0  = (_Float16*)pool;
    _Float16* s_valT = (_Float16*)pool;
    __shared__ float4 s_min[MR];
    __shared__ int    s_base[MR];
    __shared__ int    s_dtab[9];
    __shared__ float  s_pred[MR][3];
    __shared__ float  s_score[MR];
    __shared__ float  s_wred[24][4];

    const int t = threadIdx.x;
    const int wave = t >> 6, lane = t & 63, quad = lane >> 4, l15 = lane & 15;
    const int wave27 = wave * 27;
    const int rowbase = blockIdx.x * MR;

    if (t < MR) {
        int row = rowbase + t;
        s_min[t] = mlp_in[row];
        s_score[t] = scoreg[row];
        int b = row >> 15;
        int2 p = ihiw[row];
        s_base[t] = ((b * 66 + p.x) * 66 + p.y) * 64;
    }
    if (t < 9) { int di = t / 3; s_dtab[t] = (di * 66 + (t - 3 * di)) * 64; }
    if (t < MR * 3) s_pred[t / 3][t % 3] = 0.0f;
    __syncthreads();

    // ---- h0 (4->256) fp32 VALU -> LDS f16
    {
        float w0 = iw0[t], w1 = iw0[256 + t], w2 = iw0[512 + t], w3 = iw0[768 + t];
        float bb = ib0[t];
        #pragma unroll 4
        for (int r = 0; r < MR; ++r) {
            float4 m = s_min[r];
            s_h0[r * H0S + t] =
                (_Float16)gelu_f(fmaf(m.x, w0, fmaf(m.y, w1, fmaf(m.z, w2, fmaf(m.w, w3, bb)))));
        }
    }
    __syncthreads();

    // ---- h1 (256->256) MFMA; A from s_h0, result written back into same LDS region
    {
        f16x8 a[2][8];
        #pragma unroll
        for (int rt = 0; rt < 2; ++rt)
            #pragma unroll
            for (int kf = 0; kf < 8; ++kf)
                a[rt][kf] = *(const f16x8*)(s_h0 + (rt * 16 + l15) * H0S + kf * 32 + quad * 8);
        __syncthreads();   // all h0 reads done before overwrite

        #pragma unroll 1
        for (int c = 0; c < 4; ++c) {
            int col = (wave * 4 + c) * 16 + l15;
            f16x8 b[8];
            #pragma unroll
            for (int kf = 0; kf < 8; ++kf)
                b[kf] = *(const f16x8*)(w1t + col * 256 + kf * 32 + quad * 8);
            f32x4 acc0 = {0.f, 0.f, 0.f, 0.f};
            f32x4 acc1 = {0.f, 0.f, 0.f, 0.f};
            #pragma unroll
            for (int kf = 0; kf < 8; ++kf) {
                acc0 = __builtin_amdgcn_mfma_f32_16x16x32_f16(a[0][kf], b[kf], acc0, 0, 0, 0);
                acc1 = __builtin_amdgcn_mfma_f32_16x16x32_f16(a[1][kf], b[kf], acc1, 0, 0, 0);
            }
            float bias = ib1[col];
            #pragma unroll
            for (int reg = 0; reg < 4; ++reg) {
                int r0 = quad * 4 + reg;
                s_h0[r0 * H0S + col]        = (_Float16)gelu_f(acc0[reg] + bias);
                s_h0[(16 + r0) * H0S + col] = (_Float16)gelu_f(acc1[reg] + bias);
            }
        }
    }
    __syncthreads();

    // ---- A3 fragments from LDS h1
    f16x8 A3[2][8];
    #pragma unroll
    for (int rt = 0; rt < 2; ++rt)
        #pragma unroll
        for (int kf = 0; kf < 8; ++kf)
            A3[rt][kf] = *(const f16x8*)(s_h0 + (rt * 16 + l15) * H0S + kf * 32 + quad * 8);
    __syncthreads();   // h1 reads done; region becomes s_valT

    // ---- value gather (row-fast lanes: conflict-free LDS writes, L2-hot global reads)
    #pragma unroll 1
    for (int i4 = t; i4 < MR * 144; i4 += 256) {
        int r = i4 & 31;
        int c4 = i4 >> 5;
        int tap = c4 >> 4;
        int cch0 = (c4 & 15) << 2;
        const float4 v = *(const float4*)(featpad + s_base[r] + s_dtab[tap] + cch0);
        _Float16* wp = s_valT + (c4 << 2) * VSTR + r;
        wp[0]        = (_Float16)v.x;
        wp[VSTR]     = (_Float16)v.y;
        wp[2 * VSTR] = (_Float16)v.z;
        wp[3 * VSTR] = (_Float16)v.w;
    }
    __syncthreads();

    // ---- GEMM3 (256->1728 permuted) + fused value-dot, software-pipelined B loads
    float p0[2][4], p1[2][4], p2[2][4];
    #pragma unroll
    for (int rt = 0; rt < 2; ++rt)
        #pragma unroll
        for (int rg = 0; rg < 4; ++rg) { p0[rt][rg] = 0.f; p1[rt][rg] = 0.f; p2[rt][rg] = 0.f; }

    {
        f16x8 bA[8], bB[8];
        float bvA, bvB;
        LOADB2(bA, bvA, 0);
        #pragma unroll 1
        for (int i = 0; i < 26; i += 2) {
            LOADB2(bB, bvB, i + 1);
            COMPUTE2(bA, bvA, i);
            LOADB2(bA, bvA, i + 2);
            COMPUTE2(bB, bvB, i + 1);
        }
        COMPUTE2(bA, bvA, 26);
    }

    // ---- reduce across 16 column-lanes, merge cross-wave
    #pragma unroll
    for (int rt = 0; rt < 2; ++rt)
        #pragma unroll
        for (int rg = 0; rg < 4; ++rg) {
            float a0 = p0[rt][rg], a1 = p1[rt][rg], a2 = p2[rt][rg];
            #pragma unroll
            for (int m = 1; m < 16; m <<= 1) {
                a0 += __shfl_xor(a0, m, 64);
                a1 += __shfl_xor(a1, m, 64);
                a2 += __shfl_xor(a2, m, 64);
            }
            if (l15 == 0) {
                int rr = rt * 16 + quad * 4 + rg;
                atomicAdd(&s_pred[rr][0], a0);
                atomicAdd(&s_pred[rr][1], a1);
                atomicAdd(&s_pred[rr][2], a2);
            }
        }
    __syncthreads();

    // ---- fused weight MLP (4->256->1): 8 bq x 3 k outputs, 4 sub-threads each
    if (t < 96) {
        int o = t >> 2, sub = t & 3;          // o = bql*3 + k
        int bql = o / 3, k = o - 3 * bql;
        float x0 = s_pred[bql * 4 + 0][k] + s_score[bql * 4 + 0];
        float x1 = s_pred[bql * 4 + 1][k] + s_score[bql * 4 + 1];
        float x2 = s_pred[bql * 4 + 2][k] + s_score[bql * 4 + 2];
        float x3 = s_pred[bql * 4 + 3][k] + s_score[bql * 4 + 3];
        float acc = 0.0f;
        int j0 = sub * 64;
        #pragma unroll 4
        for (int j = j0; j < j0 + 64; ++j) {
            float h = gelu_f(fmaf(x0, ww0[j], fmaf(x1, ww0[256 + j],
                          fmaf(x2, ww0[512 + j], fmaf(x3, ww0[768 + j], wb0[j])))));
            acc = fmaf(h, ww1[j], acc);
        }
        s_wred[o][sub] = acc;
    }
    __syncthreads();
    if (t < 24) {
        int bql = t / 3, k = t - 3 * bql;
        float r2 = s_wred[t][0] + s_wred[t][1] + s_wred[t][2] + s_wred[t][3] + wb1[0];
        out[(blockIdx.x * 8 + bql) * 3 + k] = r2;
    }
}

extern "C" void kernel_launch(void* const* d_in, const int* in_sizes, int n_in,
                              void* d_out, int out_size, void* d_ws, size_t ws_size,
                              hipStream_t stream) {
    const float* inp   = (const float*)d_in[0];
    const float* coord = (const float*)d_in[1];
    const float* scale = (const float*)d_in[2];
    const float* ew    = (const float*)d_in[3];
    const float* eb    = (const float*)d_in[4];
    const float* iw0   = (const float*)d_in[5];
    const float* ib0   = (const float*)d_in[6];
    const float* iw1   = (const float*)d_in[7];
    const float* ib1   = (const float*)d_in[8];
    const float* iw2   = (const float*)d_in[9];
    const float* ib2   = (const float*)d_in[10];
    const float* sw0   = (const float*)d_in[11];
    const float* sb0   = (const float*)d_in[12];
    const float* sw1   = (const float*)d_in[13];
    const float* sb1   = (const float*)d_in[14];
    const float* ww0   = (const float*)d_in[15];
    const float* wb0   = (const float*)d_in[16];
    const float* ww1   = (const float*)d_in[17];
    const float* wb1   = (const float*)d_in[18];
    float* out = (float*)d_out;

    char* ws = (char*)d_ws;
    float*     featpad = (float*)(ws + 0);           // 2,230,272
    float4*    mlp_in  = (float4*)(ws + 2230272);    // 1,048,576
    int2*      ihiw    = (int2*)(ws + 3278848);      //   524,288
    float*     scoreg  = (float*)(ws + 3803136);     //   262,144
    _Float16*  w1t     = (_Float16*)(ws + 4065280);  //   131,072
    _Float16*  w2t     = (_Float16*)(ws + 4196352);  //   884,736
    float*     b2p     = (float*)(ws + 5081088);     //     6,912  (end 5,088,000)

    k_pre<<<dim3(4418), dim3(256), 0, stream>>>(inp, ew, eb, coord, scale,
                                                sw0, sb0, sw1, sb1, iw1, iw2, ib2,
                                                featpad, mlp_in, ihiw, scoreg,
                                                w1t, w2t, b2p);
    k_fused<<<dim3(NROW / MR), dim3(256), 0, stream>>>(featpad, mlp_in, ihiw,
                                                       iw0, ib0, w1t, ib1, w2t, b2p,
                                                       scoreg, ww0, wb0, ww1, wb1, out);
}

// Round 5
// 249.789 us; speedup vs baseline: 16.3334x; 1.6572x over previous
//
#include <hip/hip_runtime.h>

#define QN 8192
#define CCH 64
#define NROW 65536   // B*Q*4
#define MR 64        // rows per block in k_fused
#define NBLK (NROW / MR)   // 1024
#define H0S 264      // LDS f16 stride for h0/h1 staging

typedef _Float16 f16x8 __attribute__((ext_vector_type(8)));
typedef _Float16 f16x4 __attribute__((ext_vector_type(4)));
typedef float f32x4 __attribute__((ext_vector_type(4)));

__device__ __forceinline__ float gelu_f(float x) {
    float x2 = x * x;
    float tt = fmaf(0.044715f, x2, 1.0f);
    float e = __expf(1.5957691216f * x * tt);
    float r = __builtin_amdgcn_rcpf(1.0f + e);
    return x - x * r;
}

// ---------------- K_pre: conv (blocks 0..2177) + prep (2178..2433) + cvt (2434..4417)
__global__ __launch_bounds__(256) void k_pre(const float* __restrict__ inp,
                                             const float* __restrict__ ew,
                                             const float* __restrict__ eb,
                                             const float* __restrict__ coord,
                                             const float* __restrict__ scale,
                                             const float* __restrict__ sw0,
                                             const float* __restrict__ sb0,
                                             const float* __restrict__ sw1,
                                             const float* __restrict__ sb1,
                                             const float* __restrict__ iw1,
                                             const float* __restrict__ iw2,
                                             const float* __restrict__ ib2,
                                             float* __restrict__ featpad,
                                             float4* __restrict__ mlp_in,
                                             int2* __restrict__ ihiw,
                                             float* __restrict__ scoreg,
                                             _Float16* __restrict__ w1tp,
                                             _Float16* __restrict__ w2tp,
                                             float* __restrict__ b2p) {
    const int bb = blockIdx.x;
    const int tt0 = threadIdx.x;
    if (bb < 2178) {
        // conv3x3 (3->64) + bias, zero-padded channel-LAST (B,66,66,64)
        __shared__ float s_ew[1728];
        for (int i = tt0; i < 1728; i += 256) s_ew[i] = ew[i];
        __syncthreads();
        int idx = bb * 256 + tt0;
        const int total = 2 * 66 * 66 * CCH;
        if (idx >= total) return;
        int o = idx & 63; int pix = idx >> 6;
        int xx = pix % 66; int t2 = pix / 66;
        int yy = t2 % 66;  int b = t2 / 66;
        int y = yy - 1, x = xx - 1;
        float acc = 0.0f;
        if (y >= 0 && y < 64 && x >= 0 && x < 64) {
            acc = eb[o];
            for (int i = 0; i < 3; ++i) {
                const float* ip = inp + ((b * 3 + i) * 64) * 64;
                const float* wp = s_ew + (o * 3 + i) * 9;
                #pragma unroll
                for (int ky = 0; ky < 3; ++ky) {
                    int sy = y + ky - 1;
                    if (sy < 0 || sy > 63) continue;
                    #pragma unroll
                    for (int kx = 0; kx < 3; ++kx) {
                        int sx = x + kx - 1;
                        if (sx < 0 || sx > 63) continue;
                        acc += ip[sy * 64 + sx] * wp[ky * 3 + kx];
                    }
                }
            }
        }
        featpad[idx] = acc;
    } else if (bb < 2434) {
        // per-row prep + score MLP (2->256->1) folded with sb1
        int row = (bb - 2178) * 256 + tt0;
        int v = row & 3;
        int bq = row >> 2;
        int b = bq >> 13;
        float c0 = coord[bq * 2 + 0], c1 = coord[bq * 2 + 1];
        float s0 = scale[bq * 2 + 0], s1 = scale[bq * 2 + 1];
        float s00 = scale[(b * QN) * 2 + 0];
        float s01 = scale[(b * QN) * 2 + 1];
        float rx = (1.0f - s00) / 63.0f;
        float ry = (1.0f - s01) / 63.0f;
        float vx = (v & 2) ? 1.0f : -1.0f;
        float vy = (v & 1) ? 1.0f : -1.0f;
        float cc0 = c0 + vx * rx + 1e-6f;
        float cc1 = c1 + vy * ry + 1e-6f;
        cc0 = fminf(fmaxf(cc0, -1.0f + 1e-6f), 1.0f - 1e-6f);
        cc1 = fminf(fmaxf(cc1, -1.0f + 1e-6f), 1.0f - 1e-6f);
        int ih = (int)rintf((cc0 + 1.0f) * 32.0f - 0.5f);
        int iw = (int)rintf((cc1 + 1.0f) * 32.0f - 0.5f);
        ih = min(max(ih, 0), 63);
        iw = min(max(iw, 0), 63);
        float ck0 = (2.0f * (float)ih + 1.0f) / 64.0f - 1.0f;
        float ck1 = (2.0f * (float)iw + 1.0f) / 64.0f - 1.0f;
        float rel0 = (c0 - ck0) * 64.0f;
        float rel1 = (c1 - ck1) * 64.0f;
        mlp_in[row] = make_float4(rel0, rel1, s0 * 64.0f, s1 * 64.0f);
        ihiw[row] = make_int2(ih, iw);
        float sc = sb1[0];
        #pragma unroll 4
        for (int t2 = 0; t2 < 256; ++t2) {
            float h = gelu_f(fmaf(rel0, sw0[t2], fmaf(rel1, sw0[256 + t2], sb0[t2])));
            sc = fmaf(h, sw1[t2], sc);
        }
        scoreg[row] = sc;
    } else {
        // weight convert to LANE-MAJOR fragment layouts (coalesced loads in k_fused).
        // w2tp[((tl*8+kf)*64+lane)*8+j] = f16(iw2[kk*1728 + n(np)]),
        //   np = tl*16+(lane&15), kk = kf*32+(lane>>4)*8+j,
        //   n(np): np = k_out*576 + tap*64 + cch -> n = (cch*9+tap)*3 + k_out
        int idx = (bb - 2434) * 256 + tt0;
        if (idx < 442368) {
            int j = idx & 7, ln = (idx >> 3) & 63, kf = (idx >> 9) & 7, tl = idx >> 12;
            int np = tl * 16 + (ln & 15);
            int kk = kf * 32 + (ln >> 4) * 8 + j;
            int k_out = np / 576;
            int rem = np - 576 * k_out;
            int tap = rem >> 6, cch = rem & 63;
            int n = (cch * 9 + tap) * 3 + k_out;
            w2tp[idx] = (_Float16)iw2[kk * 1728 + n];
            if (kf == 0 && j == 0 && (ln >> 4) == 0) b2p[np] = ib2[n];
        } else {
            int i2 = idx - 442368;
            int j = i2 & 7, ln = (i2 >> 3) & 63, kf = (i2 >> 9) & 7, ct = i2 >> 12;
            int col = ct * 16 + (ln & 15);
            int kk = kf * 32 + (ln >> 4) * 8 + j;
            w1tp[i2] = (_Float16)iw1[kk * 256 + col];
        }
    }
}

// ---------------- K_fused: h0 -> h1 (MFMA) -> GEMM3 + value-dot -> +score -> weight MLP
__global__ __launch_bounds__(256, 2) void k_fused(const float* __restrict__ featpad,
                                                  const float4* __restrict__ mlp_in,
                                                  const int2* __restrict__ ihiw,
                                                  const float* __restrict__ iw0,
                                                  const float* __restrict__ ib0,
                                                  const _Float16* __restrict__ w1tp,
                                                  const float* __restrict__ ib1,
                                                  const _Float16* __restrict__ w2tp,
                                                  const float* __restrict__ b2p,
                                                  const float* __restrict__ scoreg,
                                                  const float* __restrict__ ww0,
                                                  const float* __restrict__ wb0,
                                                  const float* __restrict__ ww1,
                                                  const float* __restrict__ wb1,
                                                  float* __restrict__ out) {
    // pool: s_valT [576][64] f16 XOR-row-swizzled = 73728 B; aliased by s_h0/h1 [64][264] f16
    __shared__ __align__(16) char pool[576 * 64 * 2];
    _Float16* s_h0   = (_Float16*)pool;
    _Float16* s_valT = (_Float16*)pool;
    __shared__ float4 s_min[MR];
    __shared__ int    s_base[MR];
    __shared__ int    s_dtab[9];
    __shared__ float  s_pred[MR][3];
    __shared__ float  s_score[MR];
    __shared__ float  s_wred[48][4];

    const int t = threadIdx.x;
    const int wave = t >> 6, lane = t & 63, quad = lane >> 4, l15 = lane & 15;
    const int rowbase = blockIdx.x * MR;

    if (t < MR) {
        int row = rowbase + t;
        s_min[t] = mlp_in[row];
        s_score[t] = scoreg[row];
        int b = row >> 15;
        int2 p = ihiw[row];
        s_base[t] = ((b * 66 + p.x) * 66 + p.y) * 64;
    }
    if (t < 9) { int di = t / 3; s_dtab[t] = (di * 66 + (t - 3 * di)) * 64; }
    if (t < MR * 3) s_pred[t / 3][t % 3] = 0.0f;
    __syncthreads();

    // ---- h0 (4->256) fp32 VALU -> LDS f16 ([64][264])
    {
        float w0 = iw0[t], w1 = iw0[256 + t], w2 = iw0[512 + t], w3 = iw0[768 + t];
        float bb = ib0[t];
        #pragma unroll 4
        for (int r = 0; r < MR; ++r) {
            float4 m = s_min[r];
            s_h0[r * H0S + t] =
                (_Float16)gelu_f(fmaf(m.x, w0, fmaf(m.y, w1, fmaf(m.z, w2, fmaf(m.w, w3, bb)))));
        }
    }
    __syncthreads();

    f16x8 a[4][8];   // A fragments: 4 row-tiles x 8 k-frags (whole 64xK for this wave)
    #pragma unroll
    for (int rt = 0; rt < 4; ++rt)
        #pragma unroll
        for (int kf = 0; kf < 8; ++kf)
            a[rt][kf] = *(const f16x8*)(s_h0 + (rt * 16 + l15) * H0S + kf * 32 + quad * 8);
    __syncthreads();   // all h0 reads done before in-place h1 writes

    // ---- h1 (256->256) MFMA; wave owns col-tiles wave*4..wave*4+3, all 64 rows
    #pragma unroll 1
    for (int c = 0; c < 4; ++c) {
        int ct = wave * 4 + c;
        f16x8 bf[8];
        #pragma unroll
        for (int kf = 0; kf < 8; ++kf)
            bf[kf] = *(const f16x8*)(w1tp + ((ct * 8 + kf) * 64 + lane) * 8);
        f32x4 acc[4] = {{0.f,0.f,0.f,0.f},{0.f,0.f,0.f,0.f},{0.f,0.f,0.f,0.f},{0.f,0.f,0.f,0.f}};
        #pragma unroll
        for (int kf = 0; kf < 8; ++kf)
            #pragma unroll
            for (int rt = 0; rt < 4; ++rt)
                acc[rt] = __builtin_amdgcn_mfma_f32_16x16x32_f16(a[rt][kf], bf[kf], acc[rt], 0, 0, 0);
        int col = ct * 16 + l15;
        float bias = ib1[col];
        #pragma unroll
        for (int rt = 0; rt < 4; ++rt)
            #pragma unroll
            for (int reg = 0; reg < 4; ++reg)
                s_h0[(rt * 16 + quad * 4 + reg) * H0S + col] = (_Float16)gelu_f(acc[rt][reg] + bias);
    }
    __syncthreads();

    // ---- A3 fragments from LDS h1 (reuse a[])
    #pragma unroll
    for (int rt = 0; rt < 4; ++rt)
        #pragma unroll
        for (int kf = 0; kf < 8; ++kf)
            a[rt][kf] = *(const f16x8*)(s_h0 + (rt * 16 + l15) * H0S + kf * 32 + quad * 8);
    __syncthreads();   // h1 reads done; region becomes s_valT

    // ---- value gather: lane = row (conflict-free swizzled LDS writes; featpad L2-hot)
    #pragma unroll 1
    for (int pp = 0; pp < 36; ++pp) {
        int c4 = wave + pp * 4;           // 0..143 across 4 waves
        int row = lane;
        int tap = c4 >> 4;
        int cch0 = (c4 & 15) << 2;
        const float4 v = *(const float4*)(featpad + s_base[row] + s_dtab[tap] + cch0);
        int cfp = c4 << 2;
        s_valT[(cfp + 0) * 64 + (row ^ (((cfp + 0) & 7) << 3))] = (_Float16)v.x;
        s_valT[(cfp + 1) * 64 + (row ^ (((cfp + 1) & 7) << 3))] = (_Float16)v.y;
        s_valT[(cfp + 2) * 64 + (row ^ (((cfp + 2) & 7) << 3))] = (_Float16)v.z;
        s_valT[(cfp + 3) * 64 + (row ^ (((cfp + 3) & 7) << 3))] = (_Float16)v.w;
    }
    __syncthreads();

    // ---- GEMM3 (256->1728 permuted cols) + fused value-dot
    // wave owns 27 col-tiles; at most 2 distinct output-k per wave -> dual accumulators
    const int tbase = wave * 27;
    const int kt0 = tbase / 36;
    int bsplit = (kt0 + 1) * 36 - tbase; if (bsplit > 27) bsplit = 27;
    const int ktB = (kt0 + 1 < 3) ? kt0 + 1 : 2;
    const int swz = (l15 & 7) << 3;

    float pA[4][4], pB[4][4];
    #pragma unroll
    for (int rt = 0; rt < 4; ++rt)
        #pragma unroll
        for (int rg = 0; rg < 4; ++rg) { pA[rt][rg] = 0.f; pB[rt][rg] = 0.f; }

    f16x8 bf[8];
    float bv;
    {   // prologue: tile tbase
        const _Float16* wp = w2tp + (size_t)(tbase * 8) * 512 + lane * 8;
        #pragma unroll
        for (int kf = 0; kf < 8; ++kf) bf[kf] = *(const f16x8*)(wp + kf * 512);
        bv = b2p[tbase * 16 + l15];
    }
    #pragma unroll 1
    for (int i = 0; i < 27; ++i) {
        f32x4 acc[4] = {{0.f,0.f,0.f,0.f},{0.f,0.f,0.f,0.f},{0.f,0.f,0.f,0.f},{0.f,0.f,0.f,0.f}};
        #pragma unroll
        for (int kf = 0; kf < 8; ++kf)
            #pragma unroll
            for (int rt = 0; rt < 4; ++rt)
                acc[rt] = __builtin_amdgcn_mfma_f32_16x16x32_f16(a[rt][kf], bf[kf], acc[rt], 0, 0, 0);
        float bvc = bv;
        int ti = tbase + i;
        if (i < 26) {   // prefetch next tile (after MFMA issue; epilogue hides latency)
            const _Float16* wp = w2tp + (size_t)((ti + 1) * 8) * 512 + lane * 8;
            #pragma unroll
            for (int kf = 0; kf < 8; ++kf) bf[kf] = *(const f16x8*)(wp + kf * 512);
            bv = b2p[(ti + 1) * 16 + l15];
        }
        int cf36 = ti - (ti / 36) * 36;
        const _Float16* vbase = s_valT + (cf36 * 16 + l15) * 64;
        if (i < bsplit) {
            #pragma unroll
            for (int rt = 0; rt < 4; ++rt) {
                f16x4 vv = *(const f16x4*)(vbase + ((rt * 16 + quad * 4) ^ swz));
                #pragma unroll
                for (int rg = 0; rg < 4; ++rg) {
                    float w = (float)vv[rg];
                    pA[rt][rg] = fmaf(acc[rt][rg], w, fmaf(bvc, w, pA[rt][rg]));
                }
            }
        } else {
            #pragma unroll
            for (int rt = 0; rt < 4; ++rt) {
                f16x4 vv = *(const f16x4*)(vbase + ((rt * 16 + quad * 4) ^ swz));
                #pragma unroll
                for (int rg = 0; rg < 4; ++rg) {
                    float w = (float)vv[rg];
                    pB[rt][rg] = fmaf(acc[rt][rg], w, fmaf(bvc, w, pB[rt][rg]));
                }
            }
        }
    }

    // ---- reduce across 16 column-lanes, merge cross-wave
    #pragma unroll
    for (int rt = 0; rt < 4; ++rt)
        #pragma unroll
        for (int rg = 0; rg < 4; ++rg) {
            float aA = pA[rt][rg], aB = pB[rt][rg];
            #pragma unroll
            for (int m = 1; m < 16; m <<= 1) {
                aA += __shfl_xor(aA, m, 64);
                aB += __shfl_xor(aB, m, 64);
            }
            if (l15 == 0) {
                int rr = rt * 16 + quad * 4 + rg;
                atomicAdd(&s_pred[rr][kt0], aA);
                atomicAdd(&s_pred[rr][ktB], aB);   // pB==0 when wave has single kt
            }
        }
    __syncthreads();

    // ---- fused weight MLP (4->256->1): 16 bq x 3 k outputs, 4 sub-threads each
    if (t < 192) {
        int o = t >> 2, sub = t & 3;          // o = bql*3 + k
        int bql = o / 3, k = o - 3 * bql;
        float x0 = s_pred[bql * 4 + 0][k] + s_score[bql * 4 + 0];
        float x1 = s_pred[bql * 4 + 1][k] + s_score[bql * 4 + 1];
        float x2 = s_pred[bql * 4 + 2][k] + s_score[bql * 4 + 2];
        float x3 = s_pred[bql * 4 + 3][k] + s_score[bql * 4 + 3];
        float acc = 0.0f;
        int j0 = sub * 64;
        #pragma unroll 4
        for (int j = j0; j < j0 + 64; ++j) {
            float h = gelu_f(fmaf(x0, ww0[j], fmaf(x1, ww0[256 + j],
                          fmaf(x2, ww0[512 + j], fmaf(x3, ww0[768 + j], wb0[j])))));
            acc = fmaf(h, ww1[j], acc);
        }
        s_wred[o][sub] = acc;
    }
    __syncthreads();
    if (t < 48) {
        int bql = t / 3, k = t - 3 * bql;
        float r2 = s_wred[t][0] + s_wred[t][1] + s_wred[t][2] + s_wred[t][3] + wb1[0];
        out[(blockIdx.x * 16 + bql) * 3 + k] = r2;
    }
}

extern "C" void kernel_launch(void* const* d_in, const int* in_sizes, int n_in,
                              void* d_out, int out_size, void* d_ws, size_t ws_size,
                              hipStream_t stream) {
    const float* inp   = (const float*)d_in[0];
    const float* coord = (const float*)d_in[1];
    const float* scale = (const float*)d_in[2];
    const float* ew    = (const float*)d_in[3];
    const float* eb    = (const float*)d_in[4];
    const float* iw0   = (const float*)d_in[5];
    const float* ib0   = (const float*)d_in[6];
    const float* iw1   = (const float*)d_in[7];
    const float* ib1   = (const float*)d_in[8];
    const float* iw2   = (const float*)d_in[9];
    const float* ib2   = (const float*)d_in[10];
    const float* sw0   = (const float*)d_in[11];
    const float* sb0   = (const float*)d_in[12];
    const float* sw1   = (const float*)d_in[13];
    const float* sb1   = (const float*)d_in[14];
    const float* ww0   = (const float*)d_in[15];
    const float* wb0   = (const float*)d_in[16];
    const float* ww1   = (const float*)d_in[17];
    const float* wb1   = (const float*)d_in[18];
    float* out = (float*)d_out;

    char* ws = (char*)d_ws;
    float*     featpad = (float*)(ws + 0);           // 2,230,272
    float4*    mlp_in  = (float4*)(ws + 2230272);    // 1,048,576
    int2*      ihiw    = (int2*)(ws + 3278848);      //   524,288
    float*     scoreg  = (float*)(ws + 3803136);     //   262,144
    _Float16*  w1tp    = (_Float16*)(ws + 4065280);  //   131,072
    _Float16*  w2tp    = (_Float16*)(ws + 4196352);  //   884,736
    float*     b2p     = (float*)(ws + 5081088);     //     6,912  (end 5,088,000)

    k_pre<<<dim3(4418), dim3(256), 0, stream>>>(inp, ew, eb, coord, scale,
                                                sw0, sb0, sw1, sb1, iw1, iw2, ib2,
                                                featpad, mlp_in, ihiw, scoreg,
                                                w1tp, w2tp, b2p);
    k_fused<<<dim3(NBLK), dim3(256), 0, stream>>>(featpad, mlp_in, ihiw,
                                                  iw0, ib0, w1tp, ib1, w2tp, b2p,
                                                  scoreg, ww0, wb0, ww1, wb1, out);
}